// Round 9
// baseline (481.704 us; speedup 1.0000x reference)
//
#include <hip/hip_runtime.h>
#include <hip/hip_bf16.h>

// ---------------------------------------------------------------------------
// GIN encoder. Residual stream in bf16 only (hb ping-pong).
// GEMMs via mfma_f32_16x16x32_bf16, pre-packed B-fragment weights.
// k_layer MFMA phases: each wave owns an nt-range and covers BOTH m-halves,
// so each B-fragment is loaded once and used twice (no cross-wave duplicate
// weight loads). Gather: 4 edges per wave-load (16-lane groups x ushort8),
// paired-node interleaved edge loops, shfl_xor reduce.
// ---------------------------------------------------------------------------

typedef short bf16x8 __attribute__((ext_vector_type(8)));
typedef unsigned short u16x8 __attribute__((ext_vector_type(8)));
typedef float f32x4 __attribute__((ext_vector_type(4)));

__device__ __forceinline__ float bs2f(unsigned short u) {
    return __uint_as_float(((unsigned)u) << 16);
}
__device__ __forceinline__ unsigned short f2bs(float f) {
    __hip_bfloat16 h = __float2bfloat16(f);
    return *reinterpret_cast<unsigned short*>(&h);
}

// ---------------- CSR build ----------------
__global__ __launch_bounds__(256) void k_hist(const int* __restrict__ dst,
                                              int* __restrict__ deg, int nE)
{
    int i = blockIdx.x * 256 + threadIdx.x;
    if (i < nE) atomicAdd(&deg[dst[i]], 1);
}

__global__ __launch_bounds__(256) void k_scanA(const int* __restrict__ deg,
                                               int* __restrict__ partials, int n)
{
    int i = blockIdx.x * 256 + threadIdx.x;
    int v = (i < n) ? deg[i] : 0;
#pragma unroll
    for (int off = 32; off >= 1; off >>= 1) v += __shfl_down(v, off, 64);
    __shared__ int ws[4];
    int wave = threadIdx.x >> 6;
    if ((threadIdx.x & 63) == 0) ws[wave] = v;
    __syncthreads();
    if (threadIdx.x == 0)
        partials[blockIdx.x] = ws[0] + ws[1] + ws[2] + ws[3];
}

__global__ __launch_bounds__(256) void k_scanC(const int* __restrict__ deg,
                                               const int* __restrict__ partials,
                                               int* __restrict__ rowptr,
                                               int* __restrict__ cursor,
                                               int n, int nb)
{
    __shared__ int sp[256];
    __shared__ int s[256];
    int t = threadIdx.x;
    int pv = (t < nb) ? partials[t] : 0;
    sp[t] = pv;
    __syncthreads();
    for (int off = 1; off < 256; off <<= 1) {
        int u = (t >= off) ? sp[t - off] : 0;
        __syncthreads();
        sp[t] += u;
        __syncthreads();
    }
    int base = (blockIdx.x == 0) ? 0 : sp[blockIdx.x - 1];
    int i = blockIdx.x * 256 + t;
    int v = (i < n) ? deg[i] : 0;
    s[t] = v;
    __syncthreads();
    for (int off = 1; off < 256; off <<= 1) {
        int u = (t >= off) ? s[t - off] : 0;
        __syncthreads();
        s[t] += u;
        __syncthreads();
    }
    int inc = s[t];
    if (i < n) {
        int ex = base + inc - v;
        rowptr[i] = ex;
        cursor[i] = ex;
        if (i == n - 1) rowptr[n] = base + inc;
    }
}

__global__ __launch_bounds__(256) void k_fill(const int* __restrict__ src,
                                              const int* __restrict__ dst,
                                              int* __restrict__ cursor,
                                              int* __restrict__ adj, int nE)
{
    int i = blockIdx.x * 256 + threadIdx.x;
    if (i < nE) {
        int pos = atomicAdd(&cursor[dst[i]], 1);
        adj[pos] = src[i];
    }
}

// ---------------- weight packing (all weights, one launch) ----------------
// frag (l,nt,kt): P[((l*Nt+nt)*Kt+kt)*64 + lane][j] =
//   W_l[kt*32+(lane>>4)*8+j][nt*16+(lane&15)]
__device__ __forceinline__ void pack_one(const float* __restrict__ W,
                                         short* __restrict__ P,
                                         int id, int Kt, int Nt)
{
    int lane = id & 63;
    int t = id >> 6;
    int kt = t % Kt; t /= Kt;
    int nt = t % Nt; int l = t / Nt;
    int K = Kt * 32, N = Nt * 16;
    const float* Wl = W + (size_t)l * K * N;
    int n = nt * 16 + (lane & 15);
    int kbase = kt * 32 + (lane >> 4) * 8;
    bf16x8 v;
#pragma unroll
    for (int j = 0; j < 8; j++)
        v[j] = (short)f2bs(Wl[(size_t)(kbase + j) * N + n]);
    *(bf16x8*)(P + (size_t)id * 8) = v;
}

#define PK1 16384   // 4 layers * Nt16 * Kt4 * 64
#define PK2 16384   // 4 layers * Nt8  * Kt8 * 64
#define PK0 2048    // 1 layer  * Nt8  * Kt4 * 64

__global__ __launch_bounds__(256) void k_pack_all(
    const float* __restrict__ mlpW1, const float* __restrict__ mlpW2,
    const float* __restrict__ W0,
    short* __restrict__ pW1, short* __restrict__ pW2, short* __restrict__ pW0)
{
    int id = blockIdx.x * 256 + threadIdx.x;
    if (id < PK1) {
        pack_one(mlpW1, pW1, id, 4, 16);
    } else if (id < PK1 + PK2) {
        pack_one(mlpW2, pW2, id - PK1, 8, 8);
    } else if (id < PK1 + PK2 + PK0) {
        pack_one(W0, pW0, id - PK1 - PK2, 4, 8);
    }
}

// ---------------- encoder: hb = bf16(x@W0 + b0) via MFMA ------------------
__global__ __launch_bounds__(256) void k_encoder(const float* __restrict__ x,
                                                 const short* __restrict__ pW0,
                                                 const float* __restrict__ b0,
                                                 unsigned short* __restrict__ hb,
                                                 int n)
{
    __shared__ unsigned short sX[32][136];
    const int t = threadIdx.x;
    const int w = t >> 6;
    const int L = t & 63;
    const int node0 = blockIdx.x * 32;

    const float4* x4 = (const float4*)x;
    for (int i = t; i < 32 * 32; i += 256) {
        int m = i >> 5, cgi = i & 31;
        int node = node0 + m;
        float4 v = make_float4(0.f, 0.f, 0.f, 0.f);
        if (node < n) v = x4[(size_t)node * 32 + cgi];
        ushort4 p;
        p.x = f2bs(v.x); p.y = f2bs(v.y); p.z = f2bs(v.z); p.w = f2bs(v.w);
        *(ushort4*)&sX[m][cgi * 4] = p;
    }
    __syncthreads();

    const int quad = L >> 4;
    const int l16 = L & 15;
    const bf16x8* base = (const bf16x8*)pW0;

    // wave w owns nt = w*2 .. w*2+1, covers both m-halves
#pragma unroll
    for (int jj = 0; jj < 2; jj++) {
        int nt = w * 2 + jj;
        bf16x8 b[4];
#pragma unroll
        for (int kt = 0; kt < 4; kt++)
            b[kt] = base[(size_t)(nt * 4 + kt) * 64 + L];
        int c = nt * 16 + l16;
        float bc = b0[c];
#pragma unroll
        for (int hh = 0; hh < 2; hh++) {
            int mh = hh * 16;
            f32x4 acc = {0.f, 0.f, 0.f, 0.f};
#pragma unroll
            for (int kt = 0; kt < 4; kt++) {
                bf16x8 a = *(const bf16x8*)&sX[mh + l16][kt * 32 + quad * 8];
                acc = __builtin_amdgcn_mfma_f32_16x16x32_bf16(a, b[kt], acc, 0, 0, 0);
            }
#pragma unroll
            for (int r = 0; r < 4; r++) {
                int node = node0 + mh + quad * 4 + r;
                if (node < n)
                    hb[(size_t)node * 128 + c] = f2bs(acc[r] + bc);
            }
        }
    }
}

// ---------------- fused GIN layer -----------------------------------------
__global__ __launch_bounds__(256, 6) void k_layer(
    const unsigned short* __restrict__ hb_in,
    unsigned short* __restrict__ hb_out,
    const int* __restrict__ rowptr, const int* __restrict__ adj,
    const short* __restrict__ pW1, const float* __restrict__ b1,
    const float* __restrict__ g1, const float* __restrict__ be1,
    const float* __restrict__ mu1, const float* __restrict__ va1,
    const short* __restrict__ pW2, const float* __restrict__ b2,
    const float* __restrict__ g2, const float* __restrict__ be2,
    const float* __restrict__ mu2, const float* __restrict__ va2,
    int n)
{
    __shared__ unsigned short sIn[32][136];    // bf16(h + sum nbr), pad 8
    __shared__ unsigned short sMid[32][264];   // bf16 MLP hidden, pad 8
    const int t = threadIdx.x;
    const int w = t >> 6;
    const int L = t & 63;
    const int node0 = blockIdx.x * 32;

    // ---- gather: wave w -> nodes w*8..w*8+7, processed as 4 pairs.
    // Lane = (edge-group g = L>>4, channel-group l16 = L&15).
    // One wave-load covers 4 edge rows (1 KB); joint path keeps 4 row loads
    // in flight; shfl_xor reduces the 4 edge groups.
    {
        const int g = L >> 4;
        const int l16 = L & 15;
        const u16x8* hb8 = (const u16x8*)hb_in;   // row = 16 x u16x8
        for (int i = 0; i < 8; i += 2) {
            const int mA = w * 8 + i;
            const int mB = mA + 1;
            const int nodeA = node0 + mA;
            const int nodeB = node0 + mB;
            const bool vA = nodeA < n, vB = nodeB < n;
            float accA[8] = {0.f,0.f,0.f,0.f,0.f,0.f,0.f,0.f};
            float accB[8] = {0.f,0.f,0.f,0.f,0.f,0.f,0.f,0.f};
            u16x8 selfA, selfB;
#pragma unroll
            for (int j = 0; j < 8; j++) { selfA[j] = 0; selfB[j] = 0; }
            int eA = 0, eAe = 0, eB = 0, eBe = 0;
            if (vA) {
                eA = rowptr[nodeA]; eAe = rowptr[nodeA + 1];
                selfA = hb8[(size_t)nodeA * 16 + l16];
            }
            if (vB) {
                eB = rowptr[nodeB]; eBe = rowptr[nodeB + 1];
                selfB = hb8[(size_t)nodeB * 16 + l16];
            }
            while (eA + 8 <= eAe && eB + 8 <= eBe) {
                int a0 = adj[eA + g], a1 = adj[eA + 4 + g];
                int b0 = adj[eB + g], b1 = adj[eB + 4 + g];
                u16x8 rA0 = hb8[(size_t)a0 * 16 + l16];
                u16x8 rA1 = hb8[(size_t)a1 * 16 + l16];
                u16x8 rB0 = hb8[(size_t)b0 * 16 + l16];
                u16x8 rB1 = hb8[(size_t)b1 * 16 + l16];
#pragma unroll
                for (int j = 0; j < 8; j++) {
                    accA[j] += bs2f(rA0[j]) + bs2f(rA1[j]);
                    accB[j] += bs2f(rB0[j]) + bs2f(rB1[j]);
                }
                eA += 8; eB += 8;
            }
            while (eA + 8 <= eAe) {
                int a0 = adj[eA + g], a1 = adj[eA + 4 + g];
                u16x8 r0 = hb8[(size_t)a0 * 16 + l16];
                u16x8 r1 = hb8[(size_t)a1 * 16 + l16];
#pragma unroll
                for (int j = 0; j < 8; j++) accA[j] += bs2f(r0[j]) + bs2f(r1[j]);
                eA += 8;
            }
            if (eA + 4 <= eAe) {
                u16x8 r = hb8[(size_t)adj[eA + g] * 16 + l16];
#pragma unroll
                for (int j = 0; j < 8; j++) accA[j] += bs2f(r[j]);
                eA += 4;
            }
            if (eA < eAe) {
                int eg = eA + g;
                if (eg < eAe) {
                    u16x8 r = hb8[(size_t)adj[eg] * 16 + l16];
#pragma unroll
                    for (int j = 0; j < 8; j++) accA[j] += bs2f(r[j]);
                }
            }
            while (eB + 8 <= eBe) {
                int b0 = adj[eB + g], b1 = adj[eB + 4 + g];
                u16x8 r0 = hb8[(size_t)b0 * 16 + l16];
                u16x8 r1 = hb8[(size_t)b1 * 16 + l16];
#pragma unroll
                for (int j = 0; j < 8; j++) accB[j] += bs2f(r0[j]) + bs2f(r1[j]);
                eB += 8;
            }
            if (eB + 4 <= eBe) {
                u16x8 r = hb8[(size_t)adj[eB + g] * 16 + l16];
#pragma unroll
                for (int j = 0; j < 8; j++) accB[j] += bs2f(r[j]);
                eB += 4;
            }
            if (eB < eBe) {
                int eg = eB + g;
                if (eg < eBe) {
                    u16x8 r = hb8[(size_t)adj[eg] * 16 + l16];
#pragma unroll
                    for (int j = 0; j < 8; j++) accB[j] += bs2f(r[j]);
                }
            }
            u16x8 oA, oB;
#pragma unroll
            for (int j = 0; j < 8; j++) {
                float a = accA[j];
                a += __shfl_xor(a, 16, 64);
                a += __shfl_xor(a, 32, 64);
                oA[j] = f2bs(a + bs2f(selfA[j]));
                float b = accB[j];
                b += __shfl_xor(b, 16, 64);
                b += __shfl_xor(b, 32, 64);
                oB[j] = f2bs(b + bs2f(selfB[j]));
            }
            if (g == 0) {
                *(u16x8*)&sIn[mA][l16 * 8] = oA;
                *(u16x8*)&sIn[mB][l16 * 8] = oB;
            }
        }
    }
    __syncthreads();

    const int quad = L >> 4;
    const int l16 = L & 15;

    // ---- phase 1: sMid = relu(BN1(sIn @ W1 + b1)), 32x256, K=128 ----
    // Wave w owns nt = w*4 .. w*4+3 and covers BOTH m-halves:
    // each B-fragment loaded once, used twice.
    {
        const bf16x8* base1 = (const bf16x8*)pW1;
#pragma unroll
        for (int j = 0; j < 4; j++) {
            int nt = w * 4 + j;
            bf16x8 b[4];
#pragma unroll
            for (int kt = 0; kt < 4; kt++)
                b[kt] = base1[(size_t)(nt * 4 + kt) * 64 + L];
            int c = nt * 16 + l16;
            float sc = g1[c] * rsqrtf(va1[c] + 1e-5f);
            float sh = (b1[c] - mu1[c]) * sc + be1[c];
#pragma unroll
            for (int hh = 0; hh < 2; hh++) {
                int mh = hh * 16;
                f32x4 acc = {0.f, 0.f, 0.f, 0.f};
#pragma unroll
                for (int kt = 0; kt < 4; kt++) {
                    bf16x8 a = *(const bf16x8*)&sIn[mh + l16][kt * 32 + quad * 8];
                    acc = __builtin_amdgcn_mfma_f32_16x16x32_bf16(a, b[kt], acc, 0, 0, 0);
                }
#pragma unroll
                for (int r = 0; r < 4; r++) {
                    float v = fmaxf(acc[r] * sc + sh, 0.f);
                    sMid[mh + quad * 4 + r][c] = f2bs(v);
                }
            }
        }
    }
    __syncthreads();

    // ---- phase 2: m = relu(BN2(sMid @ W2 + b2)); hb_out = hb_in + m ----
    // Wave w owns nt = w*2 .. w*2+1, both m-halves; B held per kh-quartet.
    {
        const bf16x8* base2 = (const bf16x8*)pW2;
#pragma unroll
        for (int jj = 0; jj < 2; jj++) {
            int nt = w * 2 + jj;
            f32x4 acc[2];
            acc[0] = (f32x4){0.f, 0.f, 0.f, 0.f};
            acc[1] = (f32x4){0.f, 0.f, 0.f, 0.f};
#pragma unroll
            for (int kh = 0; kh < 2; kh++) {
                bf16x8 b[4];
#pragma unroll
                for (int kt = 0; kt < 4; kt++)
                    b[kt] = base2[(size_t)(nt * 8 + kh * 4 + kt) * 64 + L];
#pragma unroll
                for (int hh = 0; hh < 2; hh++) {
                    int mh = hh * 16;
#pragma unroll
                    for (int kt = 0; kt < 4; kt++) {
                        bf16x8 a = *(const bf16x8*)&sMid[mh + l16][(kh * 4 + kt) * 32 + quad * 8];
                        acc[hh] = __builtin_amdgcn_mfma_f32_16x16x32_bf16(a, b[kt], acc[hh], 0, 0, 0);
                    }
                }
            }
            int c = nt * 16 + l16;
            float sc = g2[c] * rsqrtf(va2[c] + 1e-5f);
            float sh = (b2[c] - mu2[c]) * sc + be2[c];
#pragma unroll
            for (int hh = 0; hh < 2; hh++) {
#pragma unroll
                for (int r = 0; r < 4; r++) {
                    int node = node0 + hh * 16 + quad * 4 + r;
                    if (node < n) {
                        float o = fmaxf(acc[hh][r] * sc + sh, 0.f);
                        float selfv = bs2f(hb_in[(size_t)node * 128 + c]);
                        hb_out[(size_t)node * 128 + c] = f2bs(selfv + o);
                    }
                }
            }
        }
    }
}

// ---------------- pooling: run-length over sorted batch (bf16 in) ---------
__global__ __launch_bounds__(256) void k_pool(const unsigned short* __restrict__ hb,
                                              const int* __restrict__ batch,
                                              float* __restrict__ pooled, int n)
{
    int c = threadIdx.x & 127;
    int half = threadIdx.x >> 7;
    int base = blockIdx.x * 128 + half * 64;
    float acc = 0.f;
    int curg = -1;
    for (int i = 0; i < 64; i++) {
        int node = base + i;
        if (node >= n) break;
        int g = batch[node];
        if (g != curg) {
            if (curg >= 0) atomicAdd(&pooled[(size_t)curg * 128 + c], acc);
            curg = g;
            acc = 0.f;
        }
        acc += bs2f(hb[(size_t)node * 128 + c]);
    }
    if (curg >= 0) atomicAdd(&pooled[(size_t)curg * 128 + c], acc);
}

__global__ __launch_bounds__(128) void k_head(const float* __restrict__ pooled,
                                              const float* __restrict__ W1,
                                              const float* __restrict__ b1,
                                              const float* __restrict__ W2,
                                              const float* __restrict__ b2,
                                              float* __restrict__ out)
{
    __shared__ float sp[128];
    __shared__ float st[128];
    int t = threadIdx.x;
    int g = blockIdx.x;
    sp[t] = pooled[(size_t)g * 128 + t];
    __syncthreads();
    float a = 0.f;
    for (int k = 0; k < 128; k++) a += sp[k] * W1[k * 128 + t];
    st[t] = fmaxf(a + b1[t], 0.f);
    __syncthreads();
    float o = 0.f;
    for (int k = 0; k < 128; k++) o += st[k] * W2[k * 128 + t];
    out[(size_t)g * 128 + t] = o + b2[t];
}

extern "C" void kernel_launch(void* const* d_in, const int* in_sizes, int n_in,
                              void* d_out, int out_size, void* d_ws, size_t ws_size,
                              hipStream_t stream)
{
    const float* x     = (const float*)d_in[0];
    const int*   ei    = (const int*)d_in[1];
    const int*   batch = (const int*)d_in[2];
    const float* W0    = (const float*)d_in[3];
    const float* b0    = (const float*)d_in[4];
    const float* mlpW1 = (const float*)d_in[5];
    const float* mlpb1 = (const float*)d_in[6];
    const float* bn1g  = (const float*)d_in[7];
    const float* bn1b  = (const float*)d_in[8];
    const float* bn1m  = (const float*)d_in[9];
    const float* bn1v  = (const float*)d_in[10];
    const float* mlpW2 = (const float*)d_in[11];
    const float* mlpb2 = (const float*)d_in[12];
    const float* ng    = (const float*)d_in[13];
    const float* nb    = (const float*)d_in[14];
    const float* nm    = (const float*)d_in[15];
    const float* nv    = (const float*)d_in[16];
    const float* W1    = (const float*)d_in[17];
    const float* b1    = (const float*)d_in[18];
    const float* W2    = (const float*)d_in[19];
    const float* b2    = (const float*)d_in[20];
    float* out = (float*)d_out;

    const int N = in_sizes[0] / 128;
    const int E = in_sizes[1] / 2;
    const int G = out_size / 128;
    const int* srcv = ei;
    const int* dstv = ei + E;

    // workspace layout
    float* pooled = (float*)d_ws;                               // G*128 f32
    unsigned short* hbA = (unsigned short*)(pooled + (size_t)G * 128); // N*128
    unsigned short* hbB = hbA + (size_t)N * 128;                // N*128
    short* pW1 = (short*)(hbB + (size_t)N * 128);               // 4*128*256
    short* pW2 = pW1 + 131072;                                  // 4*256*128
    short* pW0 = pW2 + 131072;                                  // 128*128
    int* ints  = (int*)(pW0 + 16384);
    int* deg      = ints;
    int* rowptr   = ints + N;
    int* cursor   = ints + 2 * N + 1;
    int* partials = ints + 3 * N + 1;                           // 256
    int* adj      = ints + 3 * N + 1 + 256;                     // E

    const int nodeBlocks = (N + 31) / 32;
    const int nbScan = (N + 255) / 256;

    // ---- CSR build + weight packing ----
    hipMemsetAsync(deg, 0, (size_t)N * sizeof(int), stream);
    k_hist<<<(E + 255) / 256, 256, 0, stream>>>(dstv, deg, E);
    k_scanA<<<nbScan, 256, 0, stream>>>(deg, partials, N);
    k_scanC<<<nbScan, 256, 0, stream>>>(deg, partials, rowptr, cursor, N, nbScan);
    k_fill<<<(E + 255) / 256, 256, 0, stream>>>(srcv, dstv, cursor, adj, E);
    k_pack_all<<<(PK1 + PK2 + PK0 + 255) / 256, 256, 0, stream>>>(
        mlpW1, mlpW2, W0, pW1, pW2, pW0);

    // ---- encoder ----
    k_encoder<<<nodeBlocks, 256, 0, stream>>>(x, pW0, b0, hbA, N);

    // ---- layers (bf16 residual, ping-pong) ----
    unsigned short* hc = hbA;
    unsigned short* hn = hbB;
    for (int l = 0; l < 4; l++) {
        k_layer<<<nodeBlocks, 256, 0, stream>>>(
            hc, hn, rowptr, adj,
            pW1 + (size_t)l * 32768, mlpb1 + (size_t)l * 256,
            bn1g + (size_t)l * 256, bn1b + (size_t)l * 256,
            bn1m + (size_t)l * 256, bn1v + (size_t)l * 256,
            pW2 + (size_t)l * 32768, mlpb2 + (size_t)l * 128,
            ng + (size_t)l * 128, nb + (size_t)l * 128,
            nm + (size_t)l * 128, nv + (size_t)l * 128,
            N);
        unsigned short* tmp = hc; hc = hn; hn = tmp;
    }

    // ---- pool + head ----
    hipMemsetAsync(pooled, 0, (size_t)G * 128 * sizeof(float), stream);
    k_pool<<<(N + 127) / 128, 256, 0, stream>>>(hc, batch, pooled, N);
    k_head<<<G, 128, 0, stream>>>(pooled, W1, b1, W2, b2, out);
}

// Round 11
// 433.864 us; speedup vs baseline: 1.1103x; 1.1103x over previous
//
#include <hip/hip_runtime.h>
#include <hip/hip_bf16.h>

// ---------------------------------------------------------------------------
// GIN encoder. Residual stream in bf16 only (hb ping-pong).
// GEMMs via mfma_f32_16x16x32_bf16, pre-packed B-fragment weights.
// k_layer: gather (4 edges/wave-load, paired nodes) -> MFMA MLP ->
// epilogue staged through LDS so hb_in re-read and hb_out write are
// fully coalesced (16 B/lane).
// ---------------------------------------------------------------------------

typedef short bf16x8 __attribute__((ext_vector_type(8)));
typedef unsigned short u16x8 __attribute__((ext_vector_type(8)));
typedef float f32x4 __attribute__((ext_vector_type(4)));

__device__ __forceinline__ float bs2f(unsigned short u) {
    return __uint_as_float(((unsigned)u) << 16);
}
__device__ __forceinline__ unsigned short f2bs(float f) {
    __hip_bfloat16 h = __float2bfloat16(f);
    return *reinterpret_cast<unsigned short*>(&h);
}

// ---------------- CSR build ----------------
__global__ __launch_bounds__(256) void k_hist(const int* __restrict__ dst,
                                              int* __restrict__ deg, int nE)
{
    int i = blockIdx.x * 256 + threadIdx.x;
    if (i < nE) atomicAdd(&deg[dst[i]], 1);
}

__global__ __launch_bounds__(256) void k_scanA(const int* __restrict__ deg,
                                               int* __restrict__ partials, int n)
{
    int i = blockIdx.x * 256 + threadIdx.x;
    int v = (i < n) ? deg[i] : 0;
#pragma unroll
    for (int off = 32; off >= 1; off >>= 1) v += __shfl_down(v, off, 64);
    __shared__ int ws[4];
    int wave = threadIdx.x >> 6;
    if ((threadIdx.x & 63) == 0) ws[wave] = v;
    __syncthreads();
    if (threadIdx.x == 0)
        partials[blockIdx.x] = ws[0] + ws[1] + ws[2] + ws[3];
}

__global__ __launch_bounds__(256) void k_scanC(const int* __restrict__ deg,
                                               const int* __restrict__ partials,
                                               int* __restrict__ rowptr,
                                               int* __restrict__ cursor,
                                               int n, int nb)
{
    __shared__ int sp[256];
    __shared__ int s[256];
    int t = threadIdx.x;
    int pv = (t < nb) ? partials[t] : 0;
    sp[t] = pv;
    __syncthreads();
    for (int off = 1; off < 256; off <<= 1) {
        int u = (t >= off) ? sp[t - off] : 0;
        __syncthreads();
        sp[t] += u;
        __syncthreads();
    }
    int base = (blockIdx.x == 0) ? 0 : sp[blockIdx.x - 1];
    int i = blockIdx.x * 256 + t;
    int v = (i < n) ? deg[i] : 0;
    s[t] = v;
    __syncthreads();
    for (int off = 1; off < 256; off <<= 1) {
        int u = (t >= off) ? s[t - off] : 0;
        __syncthreads();
        s[t] += u;
        __syncthreads();
    }
    int inc = s[t];
    if (i < n) {
        int ex = base + inc - v;
        rowptr[i] = ex;
        cursor[i] = ex;
        if (i == n - 1) rowptr[n] = base + inc;
    }
}

__global__ __launch_bounds__(256) void k_fill(const int* __restrict__ src,
                                              const int* __restrict__ dst,
                                              int* __restrict__ cursor,
                                              int* __restrict__ adj, int nE)
{
    int i = blockIdx.x * 256 + threadIdx.x;
    if (i < nE) {
        int pos = atomicAdd(&cursor[dst[i]], 1);
        adj[pos] = src[i];
    }
}

// ---------------- weight packing (all weights, one launch) ----------------
__device__ __forceinline__ void pack_one(const float* __restrict__ W,
                                         short* __restrict__ P,
                                         int id, int Kt, int Nt)
{
    int lane = id & 63;
    int t = id >> 6;
    int kt = t % Kt; t /= Kt;
    int nt = t % Nt; int l = t / Nt;
    int K = Kt * 32, N = Nt * 16;
    const float* Wl = W + (size_t)l * K * N;
    int n = nt * 16 + (lane & 15);
    int kbase = kt * 32 + (lane >> 4) * 8;
    bf16x8 v;
#pragma unroll
    for (int j = 0; j < 8; j++)
        v[j] = (short)f2bs(Wl[(size_t)(kbase + j) * N + n]);
    *(bf16x8*)(P + (size_t)id * 8) = v;
}

#define PK1 16384   // 4 layers * Nt16 * Kt4 * 64
#define PK2 16384   // 4 layers * Nt8  * Kt8 * 64
#define PK0 2048    // 1 layer  * Nt8  * Kt4 * 64

__global__ __launch_bounds__(256) void k_pack_all(
    const float* __restrict__ mlpW1, const float* __restrict__ mlpW2,
    const float* __restrict__ W0,
    short* __restrict__ pW1, short* __restrict__ pW2, short* __restrict__ pW0)
{
    int id = blockIdx.x * 256 + threadIdx.x;
    if (id < PK1) {
        pack_one(mlpW1, pW1, id, 4, 16);
    } else if (id < PK1 + PK2) {
        pack_one(mlpW2, pW2, id - PK1, 8, 8);
    } else if (id < PK1 + PK2 + PK0) {
        pack_one(W0, pW0, id - PK1 - PK2, 4, 8);
    }
}

// ---------------- encoder: hb = bf16(x@W0 + b0) via MFMA ------------------
__global__ __launch_bounds__(256) void k_encoder(const float* __restrict__ x,
                                                 const short* __restrict__ pW0,
                                                 const float* __restrict__ b0,
                                                 unsigned short* __restrict__ hb,
                                                 int n)
{
    __shared__ unsigned short sX[32][136];
    const int t = threadIdx.x;
    const int w = t >> 6;
    const int L = t & 63;
    const int node0 = blockIdx.x * 32;

    const float4* x4 = (const float4*)x;
    for (int i = t; i < 32 * 32; i += 256) {
        int m = i >> 5, cgi = i & 31;
        int node = node0 + m;
        float4 v = make_float4(0.f, 0.f, 0.f, 0.f);
        if (node < n) v = x4[(size_t)node * 32 + cgi];
        ushort4 p;
        p.x = f2bs(v.x); p.y = f2bs(v.y); p.z = f2bs(v.z); p.w = f2bs(v.w);
        *(ushort4*)&sX[m][cgi * 4] = p;
    }
    __syncthreads();

    const int quad = L >> 4;
    const int l16 = L & 15;
    const bf16x8* base = (const bf16x8*)pW0;

#pragma unroll
    for (int jj = 0; jj < 2; jj++) {
        int nt = w * 2 + jj;
        bf16x8 b[4];
#pragma unroll
        for (int kt = 0; kt < 4; kt++)
            b[kt] = base[(size_t)(nt * 4 + kt) * 64 + L];
        int c = nt * 16 + l16;
        float bc = b0[c];
#pragma unroll
        for (int hh = 0; hh < 2; hh++) {
            int mh = hh * 16;
            f32x4 acc = {0.f, 0.f, 0.f, 0.f};
#pragma unroll
            for (int kt = 0; kt < 4; kt++) {
                bf16x8 a = *(const bf16x8*)&sX[mh + l16][kt * 32 + quad * 8];
                acc = __builtin_amdgcn_mfma_f32_16x16x32_bf16(a, b[kt], acc, 0, 0, 0);
            }
#pragma unroll
            for (int r = 0; r < 4; r++) {
                int node = node0 + mh + quad * 4 + r;
                if (node < n)
                    hb[(size_t)node * 128 + c] = f2bs(acc[r] + bc);
            }
        }
    }
}

// ---------------- fused GIN layer -----------------------------------------
__global__ __launch_bounds__(256, 6) void k_layer(
    const unsigned short* __restrict__ hb_in,
    unsigned short* __restrict__ hb_out,
    const int* __restrict__ rowptr, const int* __restrict__ adj,
    const short* __restrict__ pW1, const float* __restrict__ b1,
    const float* __restrict__ g1, const float* __restrict__ be1,
    const float* __restrict__ mu1, const float* __restrict__ va1,
    const short* __restrict__ pW2, const float* __restrict__ b2,
    const float* __restrict__ g2, const float* __restrict__ be2,
    const float* __restrict__ mu2, const float* __restrict__ va2,
    int n)
{
    __shared__ unsigned short sIn[32][136];    // gather out; reused for m out
    __shared__ unsigned short sMid[32][264];   // bf16 MLP hidden, pad 8
    const int t = threadIdx.x;
    const int w = t >> 6;
    const int L = t & 63;
    const int node0 = blockIdx.x * 32;

    // ---- gather: wave w -> nodes w*8..w*8+7, processed as 4 pairs.
    // Lane = (edge-group g = L>>4, channel-group l16 = L&15).
    // One wave-load covers 4 edge rows (1 KB); joint path keeps 4 row loads
    // in flight; shfl_xor reduces the 4 edge groups.
    {
        const int g = L >> 4;
        const int l16 = L & 15;
        const u16x8* hb8 = (const u16x8*)hb_in;   // row = 16 x u16x8
        for (int i = 0; i < 8; i += 2) {
            const int mA = w * 8 + i;
            const int mB = mA + 1;
            const int nodeA = node0 + mA;
            const int nodeB = node0 + mB;
            const bool vA = nodeA < n, vB = nodeB < n;
            float accA[8] = {0.f,0.f,0.f,0.f,0.f,0.f,0.f,0.f};
            float accB[8] = {0.f,0.f,0.f,0.f,0.f,0.f,0.f,0.f};
            u16x8 selfA, selfB;
#pragma unroll
            for (int j = 0; j < 8; j++) { selfA[j] = 0; selfB[j] = 0; }
            int eA = 0, eAe = 0, eB = 0, eBe = 0;
            if (vA) {
                eA = rowptr[nodeA]; eAe = rowptr[nodeA + 1];
                selfA = hb8[(size_t)nodeA * 16 + l16];
            }
            if (vB) {
                eB = rowptr[nodeB]; eBe = rowptr[nodeB + 1];
                selfB = hb8[(size_t)nodeB * 16 + l16];
            }
            while (eA + 8 <= eAe && eB + 8 <= eBe) {
                int a0 = adj[eA + g], a1 = adj[eA + 4 + g];
                int b0 = adj[eB + g], b1 = adj[eB + 4 + g];
                u16x8 rA0 = hb8[(size_t)a0 * 16 + l16];
                u16x8 rA1 = hb8[(size_t)a1 * 16 + l16];
                u16x8 rB0 = hb8[(size_t)b0 * 16 + l16];
                u16x8 rB1 = hb8[(size_t)b1 * 16 + l16];
#pragma unroll
                for (int j = 0; j < 8; j++) {
                    accA[j] += bs2f(rA0[j]) + bs2f(rA1[j]);
                    accB[j] += bs2f(rB0[j]) + bs2f(rB1[j]);
                }
                eA += 8; eB += 8;
            }
            while (eA + 8 <= eAe) {
                int a0 = adj[eA + g], a1 = adj[eA + 4 + g];
                u16x8 r0 = hb8[(size_t)a0 * 16 + l16];
                u16x8 r1 = hb8[(size_t)a1 * 16 + l16];
#pragma unroll
                for (int j = 0; j < 8; j++) accA[j] += bs2f(r0[j]) + bs2f(r1[j]);
                eA += 8;
            }
            if (eA + 4 <= eAe) {
                u16x8 r = hb8[(size_t)adj[eA + g] * 16 + l16];
#pragma unroll
                for (int j = 0; j < 8; j++) accA[j] += bs2f(r[j]);
                eA += 4;
            }
            if (eA < eAe) {
                int eg = eA + g;
                if (eg < eAe) {
                    u16x8 r = hb8[(size_t)adj[eg] * 16 + l16];
#pragma unroll
                    for (int j = 0; j < 8; j++) accA[j] += bs2f(r[j]);
                }
            }
            while (eB + 8 <= eBe) {
                int b0 = adj[eB + g], b1 = adj[eB + 4 + g];
                u16x8 r0 = hb8[(size_t)b0 * 16 + l16];
                u16x8 r1 = hb8[(size_t)b1 * 16 + l16];
#pragma unroll
                for (int j = 0; j < 8; j++) accB[j] += bs2f(r0[j]) + bs2f(r1[j]);
                eB += 8;
            }
            if (eB + 4 <= eBe) {
                u16x8 r = hb8[(size_t)adj[eB + g] * 16 + l16];
#pragma unroll
                for (int j = 0; j < 8; j++) accB[j] += bs2f(r[j]);
                eB += 4;
            }
            if (eB < eBe) {
                int eg = eB + g;
                if (eg < eBe) {
                    u16x8 r = hb8[(size_t)adj[eg] * 16 + l16];
#pragma unroll
                    for (int j = 0; j < 8; j++) accB[j] += bs2f(r[j]);
                }
            }
            u16x8 oA, oB;
#pragma unroll
            for (int j = 0; j < 8; j++) {
                float a = accA[j];
                a += __shfl_xor(a, 16, 64);
                a += __shfl_xor(a, 32, 64);
                oA[j] = f2bs(a + bs2f(selfA[j]));
                float b = accB[j];
                b += __shfl_xor(b, 16, 64);
                b += __shfl_xor(b, 32, 64);
                oB[j] = f2bs(b + bs2f(selfB[j]));
            }
            if (g == 0) {
                *(u16x8*)&sIn[mA][l16 * 8] = oA;
                *(u16x8*)&sIn[mB][l16 * 8] = oB;
            }
        }
    }
    __syncthreads();

    const int quad = L >> 4;
    const int l16 = L & 15;

    // ---- phase 1: sMid = relu(BN1(sIn @ W1 + b1)), 32x256, K=128 ----
    // Wave w owns nt = w*4 .. w*4+3 and covers BOTH m-halves.
    {
        const bf16x8* base1 = (const bf16x8*)pW1;
#pragma unroll
        for (int j = 0; j < 4; j++) {
            int nt = w * 4 + j;
            bf16x8 b[4];
#pragma unroll
            for (int kt = 0; kt < 4; kt++)
                b[kt] = base1[(size_t)(nt * 4 + kt) * 64 + L];
            int c = nt * 16 + l16;
            float sc = g1[c] * rsqrtf(va1[c] + 1e-5f);
            float sh = (b1[c] - mu1[c]) * sc + be1[c];
#pragma unroll
            for (int hh = 0; hh < 2; hh++) {
                int mh = hh * 16;
                f32x4 acc = {0.f, 0.f, 0.f, 0.f};
#pragma unroll
                for (int kt = 0; kt < 4; kt++) {
                    bf16x8 a = *(const bf16x8*)&sIn[mh + l16][kt * 32 + quad * 8];
                    acc = __builtin_amdgcn_mfma_f32_16x16x32_bf16(a, b[kt], acc, 0, 0, 0);
                }
#pragma unroll
                for (int r = 0; r < 4; r++) {
                    float v = fmaxf(acc[r] * sc + sh, 0.f);
                    sMid[mh + quad * 4 + r][c] = f2bs(v);
                }
            }
        }
    }
    __syncthreads();

    // ---- phase 2: m = relu(BN2(sMid @ W2 + b2)) -> staged into sIn ----
    // Wave w owns nt = w*2 .. w*2+1, both m-halves; B held per kh-quartet.
    {
        const bf16x8* base2 = (const bf16x8*)pW2;
#pragma unroll
        for (int jj = 0; jj < 2; jj++) {
            int nt = w * 2 + jj;
            f32x4 acc[2];
            acc[0] = (f32x4){0.f, 0.f, 0.f, 0.f};
            acc[1] = (f32x4){0.f, 0.f, 0.f, 0.f};
#pragma unroll
            for (int kh = 0; kh < 2; kh++) {
                bf16x8 b[4];
#pragma unroll
                for (int kt = 0; kt < 4; kt++)
                    b[kt] = base2[(size_t)(nt * 8 + kh * 4 + kt) * 64 + L];
#pragma unroll
                for (int hh = 0; hh < 2; hh++) {
                    int mh = hh * 16;
#pragma unroll
                    for (int kt = 0; kt < 4; kt++) {
                        bf16x8 a = *(const bf16x8*)&sMid[mh + l16][(kh * 4 + kt) * 32 + quad * 8];
                        acc[hh] = __builtin_amdgcn_mfma_f32_16x16x32_bf16(a, b[kt], acc[hh], 0, 0, 0);
                    }
                }
            }
            int c = nt * 16 + l16;
            float sc = g2[c] * rsqrtf(va2[c] + 1e-5f);
            float sh = (b2[c] - mu2[c]) * sc + be2[c];
#pragma unroll
            for (int hh = 0; hh < 2; hh++) {
#pragma unroll
                for (int r = 0; r < 4; r++) {
                    float o = fmaxf(acc[hh][r] * sc + sh, 0.f);
                    sIn[hh * 16 + quad * 4 + r][c] = f2bs(o);
                }
            }
        }
    }
    __syncthreads();

    // ---- coalesced epilogue: hb_out = hb_in + m (16 B/lane streams) ----
    {
        const u16x8* hb8 = (const u16x8*)hb_in;
#pragma unroll
        for (int idx = t; idx < 512; idx += 256) {
            int row = idx >> 4, seg = idx & 15;
            int node = node0 + row;
            if (node < n) {
                u16x8 m = *(const u16x8*)&sIn[row][seg * 8];
                u16x8 s = hb8[(size_t)node * 16 + seg];
                u16x8 o;
#pragma unroll
                for (int j = 0; j < 8; j++)
                    o[j] = f2bs(bs2f(s[j]) + bs2f(m[j]));
                *(u16x8*)(hb_out + (size_t)node * 128 + seg * 8) = o;
            }
        }
    }
}

// ---------------- pooling: run-length over sorted batch (bf16 in) ---------
__global__ __launch_bounds__(256) void k_pool(const unsigned short* __restrict__ hb,
                                              const int* __restrict__ batch,
                                              float* __restrict__ pooled, int n)
{
    int c = threadIdx.x & 127;
    int half = threadIdx.x >> 7;
    int base = blockIdx.x * 128 + half * 64;
    float acc = 0.f;
    int curg = -1;
    for (int i = 0; i < 64; i++) {
        int node = base + i;
        if (node >= n) break;
        int g = batch[node];
        if (g != curg) {
            if (curg >= 0) atomicAdd(&pooled[(size_t)curg * 128 + c], acc);
            curg = g;
            acc = 0.f;
        }
        acc += bs2f(hb[(size_t)node * 128 + c]);
    }
    if (curg >= 0) atomicAdd(&pooled[(size_t)curg * 128 + c], acc);
}

__global__ __launch_bounds__(128) void k_head(const float* __restrict__ pooled,
                                              const float* __restrict__ W1,
                                              const float* __restrict__ b1,
                                              const float* __restrict__ W2,
                                              const float* __restrict__ b2,
                                              float* __restrict__ out)
{
    __shared__ float sp[128];
    __shared__ float st[128];
    int t = threadIdx.x;
    int g = blockIdx.x;
    sp[t] = pooled[(size_t)g * 128 + t];
    __syncthreads();
    float a = 0.f;
    for (int k = 0; k < 128; k++) a += sp[k] * W1[k * 128 + t];
    st[t] = fmaxf(a + b1[t], 0.f);
    __syncthreads();
    float o = 0.f;
    for (int k = 0; k < 128; k++) o += st[k] * W2[k * 128 + t];
    out[(size_t)g * 128 + t] = o + b2[t];
}

extern "C" void kernel_launch(void* const* d_in, const int* in_sizes, int n_in,
                              void* d_out, int out_size, void* d_ws, size_t ws_size,
                              hipStream_t stream)
{
    const float* x     = (const float*)d_in[0];
    const int*   ei    = (const int*)d_in[1];
    const int*   batch = (const int*)d_in[2];
    const float* W0    = (const float*)d_in[3];
    const float* b0    = (const float*)d_in[4];
    const float* mlpW1 = (const float*)d_in[5];
    const float* mlpb1 = (const float*)d_in[6];
    const float* bn1g  = (const float*)d_in[7];
    const float* bn1b  = (const float*)d_in[8];
    const float* bn1m  = (const float*)d_in[9];
    const float* bn1v  = (const float*)d_in[10];
    const float* mlpW2 = (const float*)d_in[11];
    const float* mlpb2 = (const float*)d_in[12];
    const float* ng    = (const float*)d_in[13];
    const float* nb    = (const float*)d_in[14];
    const float* nm    = (const float*)d_in[15];
    const float* nv    = (const float*)d_in[16];
    const float* W1    = (const float*)d_in[17];
    const float* b1    = (const float*)d_in[18];
    const float* W2    = (const float*)d_in[19];
    const float* b2    = (const float*)d_in[20];
    float* out = (float*)d_out;

    const int N = in_sizes[0] / 128;
    const int E = in_sizes[1] / 2;
    const int G = out_size / 128;
    const int* srcv = ei;
    const int* dstv = ei + E;

    // workspace layout
    float* pooled = (float*)d_ws;                               // G*128 f32
    unsigned short* hbA = (unsigned short*)(pooled + (size_t)G * 128); // N*128
    unsigned short* hbB = hbA + (size_t)N * 128;                // N*128
    short* pW1 = (short*)(hbB + (size_t)N * 128);               // 4*128*256
    short* pW2 = pW1 + 131072;                                  // 4*256*128
    short* pW0 = pW2 + 131072;                                  // 128*128
    int* ints  = (int*)(pW0 + 16384);
    int* deg      = ints;
    int* rowptr   = ints + N;
    int* cursor   = ints + 2 * N + 1;
    int* partials = ints + 3 * N + 1;                           // 256
    int* adj      = ints + 3 * N + 1 + 256;                     // E

    const int nodeBlocks = (N + 31) / 32;
    const int nbScan = (N + 255) / 256;

    // ---- CSR build + weight packing ----
    hipMemsetAsync(deg, 0, (size_t)N * sizeof(int), stream);
    k_hist<<<(E + 255) / 256, 256, 0, stream>>>(dstv, deg, E);
    k_scanA<<<nbScan, 256, 0, stream>>>(deg, partials, N);
    k_scanC<<<nbScan, 256, 0, stream>>>(deg, partials, rowptr, cursor, N, nbScan);
    k_fill<<<(E + 255) / 256, 256, 0, stream>>>(srcv, dstv, cursor, adj, E);
    k_pack_all<<<(PK1 + PK2 + PK0 + 255) / 256, 256, 0, stream>>>(
        mlpW1, mlpW2, W0, pW1, pW2, pW0);

    // ---- encoder ----
    k_encoder<<<nodeBlocks, 256, 0, stream>>>(x, pW0, b0, hbA, N);

    // ---- layers (bf16 residual, ping-pong) ----
    unsigned short* hc = hbA;
    unsigned short* hn = hbB;
    for (int l = 0; l < 4; l++) {
        k_layer<<<nodeBlocks, 256, 0, stream>>>(
            hc, hn, rowptr, adj,
            pW1 + (size_t)l * 32768, mlpb1 + (size_t)l * 256,
            bn1g + (size_t)l * 256, bn1b + (size_t)l * 256,
            bn1m + (size_t)l * 256, bn1v + (size_t)l * 256,
            pW2 + (size_t)l * 32768, mlpb2 + (size_t)l * 128,
            ng + (size_t)l * 128, nb + (size_t)l * 128,
            nm + (size_t)l * 128, nv + (size_t)l * 128,
            N);
        unsigned short* tmp = hc; hc = hn; hn = tmp;
    }

    // ---- pool + head ----
    hipMemsetAsync(pooled, 0, (size_t)G * 128 * sizeof(float), stream);
    k_pool<<<(N + 127) / 128, 256, 0, stream>>>(hc, batch, pooled, N);
    k_head<<<G, 128, 0, stream>>>(pooled, W1, b1, W2, b2, out);
}

// Round 12
// 411.714 us; speedup vs baseline: 1.1700x; 1.0538x over previous
//
#include <hip/hip_runtime.h>
#include <hip/hip_bf16.h>

// ---------------------------------------------------------------------------
// GIN encoder. Residual stream in bf16 only (ping-pong A/B).
// Layer split in two kernels:
//   k_gather: agg = h + sum(neighbors), one node per wave, no LDS ->
//             max occupancy for the latency-bound random gather.
//   k_mlp:    coalesced stage of agg -> MFMA MLP (pre-packed weights) ->
//             coalesced residual epilogue, writing back into the agg buffer.
// ---------------------------------------------------------------------------

typedef short bf16x8 __attribute__((ext_vector_type(8)));
typedef unsigned short u16x8 __attribute__((ext_vector_type(8)));
typedef float f32x4 __attribute__((ext_vector_type(4)));

__device__ __forceinline__ float bs2f(unsigned short u) {
    return __uint_as_float(((unsigned)u) << 16);
}
__device__ __forceinline__ unsigned short f2bs(float f) {
    __hip_bfloat16 h = __float2bfloat16(f);
    return *reinterpret_cast<unsigned short*>(&h);
}

// packed unpack-accumulate: 8 bf16 -> 8 f32 adds with 1 shl + 1 and per pair
__device__ __forceinline__ void acc8(float* acc, u16x8 v) {
    union { u16x8 u; unsigned int w[4]; } cv;
    cv.u = v;
#pragma unroll
    for (int k = 0; k < 4; k++) {
        unsigned int d = cv.w[k];
        acc[2 * k]     += __uint_as_float(d << 16);
        acc[2 * k + 1] += __uint_as_float(d & 0xffff0000u);
    }
}

// ---------------- CSR build ----------------
__global__ __launch_bounds__(256) void k_hist(const int* __restrict__ dst,
                                              int* __restrict__ deg, int nE)
{
    int i = blockIdx.x * 256 + threadIdx.x;
    if (i < nE) atomicAdd(&deg[dst[i]], 1);
}

__global__ __launch_bounds__(256) void k_scanA(const int* __restrict__ deg,
                                               int* __restrict__ partials, int n)
{
    int i = blockIdx.x * 256 + threadIdx.x;
    int v = (i < n) ? deg[i] : 0;
#pragma unroll
    for (int off = 32; off >= 1; off >>= 1) v += __shfl_down(v, off, 64);
    __shared__ int ws[4];
    int wave = threadIdx.x >> 6;
    if ((threadIdx.x & 63) == 0) ws[wave] = v;
    __syncthreads();
    if (threadIdx.x == 0)
        partials[blockIdx.x] = ws[0] + ws[1] + ws[2] + ws[3];
}

__global__ __launch_bounds__(256) void k_scanC(const int* __restrict__ deg,
                                               const int* __restrict__ partials,
                                               int* __restrict__ rowptr,
                                               int* __restrict__ cursor,
                                               int n, int nb)
{
    __shared__ int sp[256];
    __shared__ int s[256];
    int t = threadIdx.x;
    int pv = (t < nb) ? partials[t] : 0;
    sp[t] = pv;
    __syncthreads();
    for (int off = 1; off < 256; off <<= 1) {
        int u = (t >= off) ? sp[t - off] : 0;
        __syncthreads();
        sp[t] += u;
        __syncthreads();
    }
    int base = (blockIdx.x == 0) ? 0 : sp[blockIdx.x - 1];
    int i = blockIdx.x * 256 + t;
    int v = (i < n) ? deg[i] : 0;
    s[t] = v;
    __syncthreads();
    for (int off = 1; off < 256; off <<= 1) {
        int u = (t >= off) ? s[t - off] : 0;
        __syncthreads();
        s[t] += u;
        __syncthreads();
    }
    int inc = s[t];
    if (i < n) {
        int ex = base + inc - v;
        rowptr[i] = ex;
        cursor[i] = ex;
        if (i == n - 1) rowptr[n] = base + inc;
    }
}

__global__ __launch_bounds__(256) void k_fill(const int* __restrict__ src,
                                              const int* __restrict__ dst,
                                              int* __restrict__ cursor,
                                              int* __restrict__ adj, int nE)
{
    int i = blockIdx.x * 256 + threadIdx.x;
    if (i < nE) {
        int pos = atomicAdd(&cursor[dst[i]], 1);
        adj[pos] = src[i];
    }
}

// ---------------- weight packing (all weights, one launch) ----------------
__device__ __forceinline__ void pack_one(const float* __restrict__ W,
                                         short* __restrict__ P,
                                         int id, int Kt, int Nt)
{
    int lane = id & 63;
    int t = id >> 6;
    int kt = t % Kt; t /= Kt;
    int nt = t % Nt; int l = t / Nt;
    int K = Kt * 32, N = Nt * 16;
    const float* Wl = W + (size_t)l * K * N;
    int n = nt * 16 + (lane & 15);
    int kbase = kt * 32 + (lane >> 4) * 8;
    bf16x8 v;
#pragma unroll
    for (int j = 0; j < 8; j++)
        v[j] = (short)f2bs(Wl[(size_t)(kbase + j) * N + n]);
    *(bf16x8*)(P + (size_t)id * 8) = v;
}

#define PK1 16384   // 4 layers * Nt16 * Kt4 * 64
#define PK2 16384   // 4 layers * Nt8  * Kt8 * 64
#define PK0 2048    // 1 layer  * Nt8  * Kt4 * 64

__global__ __launch_bounds__(256) void k_pack_all(
    const float* __restrict__ mlpW1, const float* __restrict__ mlpW2,
    const float* __restrict__ W0,
    short* __restrict__ pW1, short* __restrict__ pW2, short* __restrict__ pW0)
{
    int id = blockIdx.x * 256 + threadIdx.x;
    if (id < PK1) {
        pack_one(mlpW1, pW1, id, 4, 16);
    } else if (id < PK1 + PK2) {
        pack_one(mlpW2, pW2, id - PK1, 8, 8);
    } else if (id < PK1 + PK2 + PK0) {
        pack_one(W0, pW0, id - PK1 - PK2, 4, 8);
    }
}

// ---------------- encoder: hb = bf16(x@W0 + b0) via MFMA ------------------
__global__ __launch_bounds__(256) void k_encoder(const float* __restrict__ x,
                                                 const short* __restrict__ pW0,
                                                 const float* __restrict__ b0,
                                                 unsigned short* __restrict__ hb,
                                                 int n)
{
    __shared__ unsigned short sX[32][136];
    const int t = threadIdx.x;
    const int w = t >> 6;
    const int L = t & 63;
    const int node0 = blockIdx.x * 32;

    const float4* x4 = (const float4*)x;
    for (int i = t; i < 32 * 32; i += 256) {
        int m = i >> 5, cgi = i & 31;
        int node = node0 + m;
        float4 v = make_float4(0.f, 0.f, 0.f, 0.f);
        if (node < n) v = x4[(size_t)node * 32 + cgi];
        ushort4 p;
        p.x = f2bs(v.x); p.y = f2bs(v.y); p.z = f2bs(v.z); p.w = f2bs(v.w);
        *(ushort4*)&sX[m][cgi * 4] = p;
    }
    __syncthreads();

    const int quad = L >> 4;
    const int l16 = L & 15;
    const bf16x8* base = (const bf16x8*)pW0;

#pragma unroll
    for (int jj = 0; jj < 2; jj++) {
        int nt = w * 2 + jj;
        bf16x8 b[4];
#pragma unroll
        for (int kt = 0; kt < 4; kt++)
            b[kt] = base[(size_t)(nt * 4 + kt) * 64 + L];
        int c = nt * 16 + l16;
        float bc = b0[c];
#pragma unroll
        for (int hh = 0; hh < 2; hh++) {
            int mh = hh * 16;
            f32x4 acc = {0.f, 0.f, 0.f, 0.f};
#pragma unroll
            for (int kt = 0; kt < 4; kt++) {
                bf16x8 a = *(const bf16x8*)&sX[mh + l16][kt * 32 + quad * 8];
                acc = __builtin_amdgcn_mfma_f32_16x16x32_bf16(a, b[kt], acc, 0, 0, 0);
            }
#pragma unroll
            for (int r = 0; r < 4; r++) {
                int node = node0 + mh + quad * 4 + r;
                if (node < n)
                    hb[(size_t)node * 128 + c] = f2bs(acc[r] + bc);
            }
        }
    }
}

// ---------------- gather: agg = h + sum(neighbors), one node per wave -----
// Lane = (edge-group g = L>>4, channel-seg l16 = L&15); one wave-load
// covers 4 edge rows (1 KB); unroll-2 keeps 8 rows in flight; shfl_xor
// reduces the 4 edge groups. No LDS -> max occupancy.
__global__ __launch_bounds__(256) void k_gather(
    const unsigned short* __restrict__ hb_in,
    unsigned short* __restrict__ agg,
    const int* __restrict__ rowptr, const int* __restrict__ adj, int n)
{
    const int t = threadIdx.x;
    const int node = blockIdx.x * 4 + (t >> 6);
    const int L = t & 63;
    const int g = L >> 4;
    const int l16 = L & 15;
    if (node >= n) return;

    const u16x8* hb8 = (const u16x8*)hb_in;
    u16x8 self = hb8[(size_t)node * 16 + l16];
    float acc[8] = {0.f, 0.f, 0.f, 0.f, 0.f, 0.f, 0.f, 0.f};

    int e1 = rowptr[node + 1];
    int e = rowptr[node];
    for (; e + 8 <= e1; e += 8) {
        int s0 = adj[e + g];
        int s1 = adj[e + 4 + g];
        u16x8 v0 = hb8[(size_t)s0 * 16 + l16];
        u16x8 v1 = hb8[(size_t)s1 * 16 + l16];
        acc8(acc, v0);
        acc8(acc, v1);
    }
    if (e + 4 <= e1) {
        u16x8 v = hb8[(size_t)adj[e + g] * 16 + l16];
        acc8(acc, v);
        e += 4;
    }
    if (e < e1) {
        int eg = e + g;
        if (eg < e1) {
            u16x8 v = hb8[(size_t)adj[eg] * 16 + l16];
            acc8(acc, v);
        }
    }

    u16x8 o;
#pragma unroll
    for (int j = 0; j < 8; j++) {
        float v = acc[j];
        v += __shfl_xor(v, 16, 64);
        v += __shfl_xor(v, 32, 64);
        o[j] = f2bs(v + bs2f(self[j]));
    }
    if (g == 0)
        *(u16x8*)(agg + (size_t)node * 128 + l16 * 8) = o;
}

// ---------------- MLP: hb_out(=agg) = hb_self + relu(BN2(W2 relu(BN1(W1 agg))))
__global__ __launch_bounds__(256, 6) void k_mlp(
    const unsigned short* __restrict__ hb_self,
    unsigned short* __restrict__ agg,        // in: h+sum, out: new h (same buf)
    const short* __restrict__ pW1, const float* __restrict__ b1,
    const float* __restrict__ g1, const float* __restrict__ be1,
    const float* __restrict__ mu1, const float* __restrict__ va1,
    const short* __restrict__ pW2, const float* __restrict__ b2,
    const float* __restrict__ g2, const float* __restrict__ be2,
    const float* __restrict__ mu2, const float* __restrict__ va2,
    int n)
{
    __shared__ unsigned short sIn[32][136];    // staged agg; reused for m out
    __shared__ unsigned short sMid[32][264];   // bf16 MLP hidden, pad 8
    const int t = threadIdx.x;
    const int w = t >> 6;
    const int L = t & 63;
    const int node0 = blockIdx.x * 32;

    // ---- coalesced stage: agg -> sIn (16 B/lane) ----
    {
        const u16x8* ag8 = (const u16x8*)agg;
#pragma unroll
        for (int idx = t; idx < 512; idx += 256) {
            int row = idx >> 4, seg = idx & 15;
            int node = node0 + row;
            u16x8 v;
#pragma unroll
            for (int j = 0; j < 8; j++) v[j] = 0;
            if (node < n) v = ag8[(size_t)node * 16 + seg];
            *(u16x8*)&sIn[row][seg * 8] = v;
        }
    }
    __syncthreads();

    const int quad = L >> 4;
    const int l16 = L & 15;

    // ---- phase 1: sMid = relu(BN1(sIn @ W1 + b1)), 32x256, K=128 ----
    {
        const bf16x8* base1 = (const bf16x8*)pW1;
#pragma unroll
        for (int j = 0; j < 4; j++) {
            int nt = w * 4 + j;
            bf16x8 b[4];
#pragma unroll
            for (int kt = 0; kt < 4; kt++)
                b[kt] = base1[(size_t)(nt * 4 + kt) * 64 + L];
            int c = nt * 16 + l16;
            float sc = g1[c] * rsqrtf(va1[c] + 1e-5f);
            float sh = (b1[c] - mu1[c]) * sc + be1[c];
#pragma unroll
            for (int hh = 0; hh < 2; hh++) {
                int mh = hh * 16;
                f32x4 acc = {0.f, 0.f, 0.f, 0.f};
#pragma unroll
                for (int kt = 0; kt < 4; kt++) {
                    bf16x8 a = *(const bf16x8*)&sIn[mh + l16][kt * 32 + quad * 8];
                    acc = __builtin_amdgcn_mfma_f32_16x16x32_bf16(a, b[kt], acc, 0, 0, 0);
                }
#pragma unroll
                for (int r = 0; r < 4; r++) {
                    float v = fmaxf(acc[r] * sc + sh, 0.f);
                    sMid[mh + quad * 4 + r][c] = f2bs(v);
                }
            }
        }
    }
    __syncthreads();

    // ---- phase 2: m = relu(BN2(sMid @ W2 + b2)) -> staged into sIn ----
    {
        const bf16x8* base2 = (const bf16x8*)pW2;
#pragma unroll
        for (int jj = 0; jj < 2; jj++) {
            int nt = w * 2 + jj;
            f32x4 acc[2];
            acc[0] = (f32x4){0.f, 0.f, 0.f, 0.f};
            acc[1] = (f32x4){0.f, 0.f, 0.f, 0.f};
#pragma unroll
            for (int kh = 0; kh < 2; kh++) {
                bf16x8 b[4];
#pragma unroll
                for (int kt = 0; kt < 4; kt++)
                    b[kt] = base2[(size_t)(nt * 8 + kh * 4 + kt) * 64 + L];
#pragma unroll
                for (int hh = 0; hh < 2; hh++) {
                    int mh = hh * 16;
#pragma unroll
                    for (int kt = 0; kt < 4; kt++) {
                        bf16x8 a = *(const bf16x8*)&sMid[mh + l16][(kh * 4 + kt) * 32 + quad * 8];
                        acc[hh] = __builtin_amdgcn_mfma_f32_16x16x32_bf16(a, b[kt], acc[hh], 0, 0, 0);
                    }
                }
            }
            int c = nt * 16 + l16;
            float sc = g2[c] * rsqrtf(va2[c] + 1e-5f);
            float sh = (b2[c] - mu2[c]) * sc + be2[c];
#pragma unroll
            for (int hh = 0; hh < 2; hh++) {
#pragma unroll
                for (int r = 0; r < 4; r++) {
                    float o = fmaxf(acc[hh][r] * sc + sh, 0.f);
                    sIn[hh * 16 + quad * 4 + r][c] = f2bs(o);
                }
            }
        }
    }
    __syncthreads();

    // ---- coalesced epilogue: agg = hb_self + m (16 B/lane streams) ----
    {
        const u16x8* hs8 = (const u16x8*)hb_self;
#pragma unroll
        for (int idx = t; idx < 512; idx += 256) {
            int row = idx >> 4, seg = idx & 15;
            int node = node0 + row;
            if (node < n) {
                u16x8 m = *(const u16x8*)&sIn[row][seg * 8];
                u16x8 s = hs8[(size_t)node * 16 + seg];
                u16x8 o;
#pragma unroll
                for (int j = 0; j < 8; j++)
                    o[j] = f2bs(bs2f(s[j]) + bs2f(m[j]));
                *(u16x8*)(agg + (size_t)node * 128 + seg * 8) = o;
            }
        }
    }
}

// ---------------- pooling: run-length over sorted batch (bf16 in) ---------
__global__ __launch_bounds__(256) void k_pool(const unsigned short* __restrict__ hb,
                                              const int* __restrict__ batch,
                                              float* __restrict__ pooled, int n)
{
    int c = threadIdx.x & 127;
    int half = threadIdx.x >> 7;
    int base = blockIdx.x * 128 + half * 64;
    float acc = 0.f;
    int curg = -1;
    for (int i = 0; i < 64; i++) {
        int node = base + i;
        if (node >= n) break;
        int g = batch[node];
        if (g != curg) {
            if (curg >= 0) atomicAdd(&pooled[(size_t)curg * 128 + c], acc);
            curg = g;
            acc = 0.f;
        }
        acc += bs2f(hb[(size_t)node * 128 + c]);
    }
    if (curg >= 0) atomicAdd(&pooled[(size_t)curg * 128 + c], acc);
}

__global__ __launch_bounds__(128) void k_head(const float* __restrict__ pooled,
                                              const float* __restrict__ W1,
                                              const float* __restrict__ b1,
                                              const float* __restrict__ W2,
                                              const float* __restrict__ b2,
                                              float* __restrict__ out)
{
    __shared__ float sp[128];
    __shared__ float st[128];
    int t = threadIdx.x;
    int g = blockIdx.x;
    sp[t] = pooled[(size_t)g * 128 + t];
    __syncthreads();
    float a = 0.f;
    for (int k = 0; k < 128; k++) a += sp[k] * W1[k * 128 + t];
    st[t] = fmaxf(a + b1[t], 0.f);
    __syncthreads();
    float o = 0.f;
    for (int k = 0; k < 128; k++) o += st[k] * W2[k * 128 + t];
    out[(size_t)g * 128 + t] = o + b2[t];
}

extern "C" void kernel_launch(void* const* d_in, const int* in_sizes, int n_in,
                              void* d_out, int out_size, void* d_ws, size_t ws_size,
                              hipStream_t stream)
{
    const float* x     = (const float*)d_in[0];
    const int*   ei    = (const int*)d_in[1];
    const int*   batch = (const int*)d_in[2];
    const float* W0    = (const float*)d_in[3];
    const float* b0    = (const float*)d_in[4];
    const float* mlpW1 = (const float*)d_in[5];
    const float* mlpb1 = (const float*)d_in[6];
    const float* bn1g  = (const float*)d_in[7];
    const float* bn1b  = (const float*)d_in[8];
    const float* bn1m  = (const float*)d_in[9];
    const float* bn1v  = (const float*)d_in[10];
    const float* mlpW2 = (const float*)d_in[11];
    const float* mlpb2 = (const float*)d_in[12];
    const float* ng    = (const float*)d_in[13];
    const float* nb    = (const float*)d_in[14];
    const float* nm    = (const float*)d_in[15];
    const float* nv    = (const float*)d_in[16];
    const float* W1    = (const float*)d_in[17];
    const float* b1    = (const float*)d_in[18];
    const float* W2    = (const float*)d_in[19];
    const float* b2    = (const float*)d_in[20];
    float* out = (float*)d_out;

    const int N = in_sizes[0] / 128;
    const int E = in_sizes[1] / 2;
    const int G = out_size / 128;
    const int* srcv = ei;
    const int* dstv = ei + E;

    // workspace layout
    float* pooled = (float*)d_ws;                               // G*128 f32
    unsigned short* hbA = (unsigned short*)(pooled + (size_t)G * 128); // N*128
    unsigned short* hbB = hbA + (size_t)N * 128;                // N*128
    short* pW1 = (short*)(hbB + (size_t)N * 128);               // 4*128*256
    short* pW2 = pW1 + 131072;                                  // 4*256*128
    short* pW0 = pW2 + 131072;                                  // 128*128
    int* ints  = (int*)(pW0 + 16384);
    int* deg      = ints;
    int* rowptr   = ints + N;
    int* cursor   = ints + 2 * N + 1;
    int* partials = ints + 3 * N + 1;                           // 256
    int* adj      = ints + 3 * N + 1 + 256;                     // E

    const int nodeBlocks = (N + 31) / 32;
    const int nbScan = (N + 255) / 256;

    // ---- CSR build + weight packing ----
    hipMemsetAsync(deg, 0, (size_t)N * sizeof(int), stream);
    k_hist<<<(E + 255) / 256, 256, 0, stream>>>(dstv, deg, E);
    k_scanA<<<nbScan, 256, 0, stream>>>(deg, partials, N);
    k_scanC<<<nbScan, 256, 0, stream>>>(deg, partials, rowptr, cursor, N, nbScan);
    k_fill<<<(E + 255) / 256, 256, 0, stream>>>(srcv, dstv, cursor, adj, E);
    k_pack_all<<<(PK1 + PK2 + PK0 + 255) / 256, 256, 0, stream>>>(
        mlpW1, mlpW2, W0, pW1, pW2, pW0);

    // ---- encoder ----
    k_encoder<<<nodeBlocks, 256, 0, stream>>>(x, pW0, b0, hbA, N);

    // ---- layers: gather into hn, MLP reads hn+hc, writes new h into hn ----
    unsigned short* hc = hbA;
    unsigned short* hn = hbB;
    for (int l = 0; l < 4; l++) {
        k_gather<<<(N + 3) / 4, 256, 0, stream>>>(hc, hn, rowptr, adj, N);
        k_mlp<<<nodeBlocks, 256, 0, stream>>>(
            hc, hn,
            pW1 + (size_t)l * 32768, mlpb1 + (size_t)l * 256,
            bn1g + (size_t)l * 256, bn1b + (size_t)l * 256,
            bn1m + (size_t)l * 256, bn1v + (size_t)l * 256,
            pW2 + (size_t)l * 32768, mlpb2 + (size_t)l * 128,
            ng + (size_t)l * 128, nb + (size_t)l * 128,
            nm + (size_t)l * 128, nv + (size_t)l * 128,
            N);
        unsigned short* tmp = hc; hc = hn; hn = tmp;
    }

    // ---- pool + head ----
    hipMemsetAsync(pooled, 0, (size_t)G * 128 * sizeof(float), stream);
    k_pool<<<(N + 127) / 128, 256, 0, stream>>>(hc, batch, pooled, N);
    k_head<<<G, 128, 0, stream>>>(pooled, W1, b1, W2, b2, out);
}